// Round 7
// baseline (531.098 us; speedup 1.0000x reference)
//
#include <hip/hip_runtime.h>
#include <cstdint>

#define T_ 32
#define N_ 5000
#define E_ 80000
#define H_ 128
#define HD_ 512
#define C_ 10

typedef _Float16 f16;
typedef f16 f16x8 __attribute__((ext_vector_type(8)));
typedef f16 f16x4 __attribute__((ext_vector_type(4)));
typedef f16 f16x2 __attribute__((ext_vector_type(2)));
typedef float f32x4 __attribute__((ext_vector_type(4)));

#define LDA 136   // padded LDS leading dim in f16
#define NB_ 8     // CSR-build blocks per graph
#define EPS_ (E_ / NB_)  // 10000 edges per block
#define STRIPS 24 // gemm row-strips per graph (768 blocks = 3 blocks/CU, LDS-capped)
#define NBLK_ 313 // ceil(N_/16) node-blocks per graph (aggr)

__device__ inline int addpk(int a, int b) {
    f16x2 x = __builtin_bit_cast(f16x2, a);
    f16x2 y = __builtin_bit_cast(f16x2, b);
    f16x2 r = x + y;
    return __builtin_bit_cast(int, r);
}

__device__ inline float fast_tanh(float x) {
    return 1.0f - 2.0f / (__expf(2.0f * x) + 1.0f);
}

// ---------------- CSR build, LDS-atomic (no global atomics) ----------------
__global__ __launch_bounds__(256) void k_count(const int* __restrict__ ei, int* __restrict__ part) {
    __shared__ int cnt[N_];
    int blk = blockIdx.x;
    int t = blk & 31, seg = blk >> 5;
    int tid = threadIdx.x;
    for (int i = tid; i < N_; i += 256) cnt[i] = 0;
    __syncthreads();
    const int* dst = ei + (size_t)t * 2 * E_ + E_ + seg * EPS_;
    for (int e = tid * 4; e < EPS_; e += 1024) {
        int4 d = *(const int4*)&dst[e];
        atomicAdd(&cnt[d.x], 1);
        atomicAdd(&cnt[d.y], 1);
        atomicAdd(&cnt[d.z], 1);
        atomicAdd(&cnt[d.w], 1);
    }
    __syncthreads();
    int* p = part + (t * NB_ + seg) * N_;
    for (int i = tid * 4; i < N_; i += 1024) *(int4*)&p[i] = *(const int4*)&cnt[i];
}

// ---------------- scan v2: coalesced degree/fixup phases, LDS-staged scan ----------------
__global__ __launch_bounds__(256) void k_scan(int* __restrict__ part, int* __restrict__ ptr,
                                              float* __restrict__ dinv, float* __restrict__ z) {
    __shared__ int cnt[N_];      // degree, then start offset
    __shared__ int red[256];
    int t = blockIdx.x, tid = threadIdx.x;
    int base = t * N_;
    if (tid < 128) z[t * 128 + tid] = 0.0f;   // folded zinit (also the aggr zero-row source)
    int* pp = part + t * NB_ * N_;

    // Phase A: coalesced degree computation
    for (int i = tid; i < N_; i += 256) {
        int c = 0;
#pragma unroll
        for (int s = 0; s < NB_; ++s) c += pp[s * N_ + i];
        cnt[i] = c;
        dinv[base + i] = rsqrtf((float)(c + 1));  // +1 self-loop
    }
    __syncthreads();

    // Phase B: block scan over blocked 20-element runs (LDS source)
    int vals[20];
    int sum = 0;
#pragma unroll
    for (int j = 0; j < 20; ++j) {
        int i = tid * 20 + j;
        int c = (i < N_) ? cnt[i] : 0;
        vals[j] = sum;
        sum += c;
    }
    red[tid] = sum;
    __syncthreads();
    for (int off = 1; off < 256; off <<= 1) {
        int v = (tid >= off) ? red[tid - off] : 0;
        __syncthreads();
        red[tid] += v;
        __syncthreads();
    }
    int prev = (tid > 0) ? red[tid - 1] : 0;
#pragma unroll
    for (int j = 0; j < 20; ++j) {
        int i = tid * 20 + j;
        if (i < N_) cnt[i] = prev + vals[j];   // overwrite degree with start offset
    }
    __syncthreads();

    // Phase C: coalesced ptr write + per-segment running-offset fixup
    for (int i = tid; i < N_; i += 256) {
        int run = cnt[i];
        ptr[base + i] = run;
#pragma unroll
        for (int s = 0; s < NB_; ++s) {
            int c = pp[s * N_ + i];
            pp[s * N_ + i] = run;
            run += c;
        }
    }
}

__global__ __launch_bounds__(256) void k_scatter(const int* __restrict__ ei,
                                                 const int* __restrict__ part,
                                                 uint16_t* __restrict__ col) {
    __shared__ int cur[N_];
    int blk = blockIdx.x;
    int t = blk & 31, seg = blk >> 5;
    int tid = threadIdx.x;
    const int* off = part + (t * NB_ + seg) * N_;
    for (int i = tid * 4; i < N_; i += 1024) *(int4*)&cur[i] = *(const int4*)&off[i];
    __syncthreads();
    const int* src = ei + (size_t)t * 2 * E_ + seg * EPS_;
    const int* dst = src + E_;
    uint16_t* cl = col + (size_t)t * E_;
    for (int e = tid * 4; e < EPS_; e += 1024) {
        int4 s4 = *(const int4*)&src[e];
        int4 d4 = *(const int4*)&dst[e];
        cl[atomicAdd(&cur[d4.x], 1)] = (uint16_t)s4.x;
        cl[atomicAdd(&cur[d4.y], 1)] = (uint16_t)s4.y;
        cl[atomicAdd(&cur[d4.z], 1)] = (uint16_t)s4.z;
        cl[atomicAdd(&cur[d4.w], 1)] = (uint16_t)s4.w;
    }
}

// ---------------- weight prep: Wt[l][c][k] = (f16)W_l[k][c] ----------------
__global__ __launch_bounds__(256) void k_wprep(const float* __restrict__ W0,
                                               const float* __restrict__ W1,
                                               const float* __restrict__ W2,
                                               f16* __restrict__ Wt) {
    const float* W = (blockIdx.x == 0) ? W0 : (blockIdx.x == 1) ? W1 : W2;
    f16* dst = Wt + blockIdx.x * 16384;
    for (int idx = threadIdx.x; idx < 16384; idx += 256) {
        int c = idx >> 7, k = idx & 127;
        dst[idx] = (f16)W[k * 128 + c];
    }
}

// ---------------- MFMA GEMM v4: register-prefetch pipeline ----------------
// v3 exposed the A-tile global load every tile (stage -> barrier -> MFMA; all 4
// waves stall the full load latency at the same barrier, only 2 blocks/CU).
// v4: issue next tile's global loads at the TOP of the loop into registers;
// consume them with ds_write AFTER the store barrier -> load latency hides
// under MFMA + epilogue + store. Same 4 barriers/tile, same single As buffer.
// STRIPS 24 (768 blocks = 3 blocks/CU, the 52KB-LDS cap); launch_bounds(256,3)
// keeps VGPR within the 3-wave/SIMD budget.
template <bool F32IN>
__global__ __launch_bounds__(256, 3) void k_gemm(const void* __restrict__ in_,
                                                 const f16* __restrict__ Wt,  // [c][k]
                                                 const float* __restrict__ dinv,
                                                 f16* __restrict__ g) {
    __shared__ f16 Ws[128 * LDA];
    __shared__ f16 As[64 * LDA];
    int b = blockIdx.x;
    int t = b & 31;
    int strip = b >> 5;
    int tid = threadIdx.x;

    // stage Wt -> Ws ONCE (first barrier is below, after prologue A-stage)
    {
        int c = tid >> 1, hf = tid & 1;
        const f16* src = Wt + c * 128 + hf * 64;
        f16* dst = Ws + c * LDA + hf * 64;
#pragma unroll
        for (int j = 0; j < 8; ++j) *(f16x8*)&dst[j * 8] = *(const f16x8*)&src[j * 8];
    }

    int w = tid >> 6, lane = tid & 63;
    int m = lane & 15, q = lane >> 4;
    int rw = w * 16;
    int sr = tid >> 2, skq = (tid & 3) * 32;   // staging row / k-quarter

    // prologue: stage tile 'strip' (rows strip*64+sr <= 23*64+63 < N_, always valid)
    {
        f16* dst = As + sr * LDA + skq;
        if (F32IN) {
            const float* src = (const float*)in_ + ((size_t)(t * N_ + strip * 64 + sr)) * H_ + skq;
#pragma unroll
            for (int j = 0; j < 8; ++j) {
                float4 v = *(const float4*)&src[j * 4];
                dst[j * 4 + 0] = (f16)v.x;
                dst[j * 4 + 1] = (f16)v.y;
                dst[j * 4 + 2] = (f16)v.z;
                dst[j * 4 + 3] = (f16)v.w;
            }
        } else {
            const f16* src = (const f16*)in_ + ((size_t)(t * N_ + strip * 64 + sr)) * H_ + skq;
#pragma unroll
            for (int j = 0; j < 4; ++j) *(f16x8*)&dst[j * 8] = *(const f16x8*)&src[j * 8];
        }
    }
    __syncthreads();  // Ws + first A visible

    for (int tile = strip; tile < 79; tile += STRIPS) {
        int r0 = tile * 64;
        int tn = tile + STRIPS;
        bool havn = tn < 79;          // block-uniform

        // issue next tile's global loads EARLY (regs); consumed after store barrier
        float4 nf0, nf1, nf2, nf3, nf4, nf5, nf6, nf7;
        f16x8 nh0, nh1, nh2, nh3;
        if (havn) {
            bool valid = (tn * 64 + sr) < N_;
            if (F32IN) {
                const float* src = (const float*)in_ + ((size_t)(t * N_ + tn * 64 + sr)) * H_ + skq;
                float4 zz = make_float4(0.f, 0.f, 0.f, 0.f);
                nf0 = valid ? *(const float4*)&src[0]  : zz;
                nf1 = valid ? *(const float4*)&src[4]  : zz;
                nf2 = valid ? *(const float4*)&src[8]  : zz;
                nf3 = valid ? *(const float4*)&src[12] : zz;
                nf4 = valid ? *(const float4*)&src[16] : zz;
                nf5 = valid ? *(const float4*)&src[20] : zz;
                nf6 = valid ? *(const float4*)&src[24] : zz;
                nf7 = valid ? *(const float4*)&src[28] : zz;
            } else {
                const f16* src = (const f16*)in_ + ((size_t)(t * N_ + tn * 64 + sr)) * H_ + skq;
                f16x8 zz = {};
                nh0 = valid ? *(const f16x8*)&src[0]  : zz;
                nh1 = valid ? *(const f16x8*)&src[8]  : zz;
                nh2 = valid ? *(const f16x8*)&src[16] : zz;
                nh3 = valid ? *(const f16x8*)&src[24] : zz;
            }
        }

        f32x4 acc[8];
#pragma unroll
        for (int n = 0; n < 8; ++n) acc[n] = (f32x4){0.f, 0.f, 0.f, 0.f};
#pragma unroll
        for (int kb = 0; kb < 4; ++kb) {
            f16x8 aF = *(const f16x8*)&As[(rw + m) * LDA + kb * 32 + q * 8];
#pragma unroll
            for (int n = 0; n < 8; ++n) {
                f16x8 bF = *(const f16x8*)&Ws[(n * 16 + m) * LDA + kb * 32 + q * 8];
                acc[n] = __builtin_amdgcn_mfma_f32_16x16x32_f16(aF, bF, acc[n], 0, 0, 0);
            }
        }
        __syncthreads();  // all MFMA reads of As done; reuse As for epilogue

#pragma unroll
        for (int i = 0; i < 4; ++i) {
            int rr = rw + q * 4 + i;
            int gr = r0 + rr;
            float d = dinv[t * N_ + (gr < N_ ? gr : N_ - 1)];
#pragma unroll
            for (int n = 0; n < 8; ++n)
                As[rr * LDA + n * 16 + m] = (f16)(acc[n][i] * d);
        }
        __syncthreads();
        if (r0 + sr < N_) {
            f16* dst = g + ((size_t)(t * N_ + r0 + sr)) * H_ + skq;
            const f16* src = As + sr * LDA + skq;
#pragma unroll
            for (int j = 0; j < 4; ++j) *(f16x8*)&dst[j * 8] = *(const f16x8*)&src[j * 8];
        }
        __syncthreads();  // store reads done; As free for next tile
        if (havn) {
            f16* dst = As + sr * LDA + skq;
            if (F32IN) {
                dst[0]  = (f16)nf0.x; dst[1]  = (f16)nf0.y; dst[2]  = (f16)nf0.z; dst[3]  = (f16)nf0.w;
                dst[4]  = (f16)nf1.x; dst[5]  = (f16)nf1.y; dst[6]  = (f16)nf1.z; dst[7]  = (f16)nf1.w;
                dst[8]  = (f16)nf2.x; dst[9]  = (f16)nf2.y; dst[10] = (f16)nf2.z; dst[11] = (f16)nf2.w;
                dst[12] = (f16)nf3.x; dst[13] = (f16)nf3.y; dst[14] = (f16)nf3.z; dst[15] = (f16)nf3.w;
                dst[16] = (f16)nf4.x; dst[17] = (f16)nf4.y; dst[18] = (f16)nf4.z; dst[19] = (f16)nf4.w;
                dst[20] = (f16)nf5.x; dst[21] = (f16)nf5.y; dst[22] = (f16)nf5.z; dst[23] = (f16)nf5.w;
                dst[24] = (f16)nf6.x; dst[25] = (f16)nf6.y; dst[26] = (f16)nf6.z; dst[27] = (f16)nf6.w;
                dst[28] = (f16)nf7.x; dst[29] = (f16)nf7.y; dst[30] = (f16)nf7.z; dst[31] = (f16)nf7.w;
            } else {
                *(f16x8*)&dst[0]  = nh0;
                *(f16x8*)&dst[8]  = nh1;
                *(f16x8*)&dst[16] = nh2;
                *(f16x8*)&dst[24] = nh3;
            }
        }
        __syncthreads();  // next A visible
    }
}

// ---------------- CSR gather v4 (reverted from v5 two-bank: compiler collapsed the
// pipeline at VGPR=48 and the overhead regressed 56.2 -> 59.8us; v4 is the measured
// best and sits near the random-gather L2 throughput ceiling) ----------------
// (1) Graph-major per-XCD block order: XCD = blk&7; one graph's gather set
//     (~2.7MB) stays resident in the 4MB XCD L2 (FETCH 105 -> 23MB).
// (2) 8-aligned edge chunks: one dwordx4 col load per 8 edges (prefetched one
//     chunk ahead); out-of-range lanes redirected via ONE cndmask to a known-
//     zero row (the z buffer: zeroed by k_scan, first written by k_reduce AFTER
//     all aggrs; row index 320000-5000*t relative to gg). Adds unconditional.
__global__ __launch_bounds__(256) void k_aggr(const int* __restrict__ ptr,
                                              const uint16_t* __restrict__ col,
                                              const f16* __restrict__ g,
                                              const float* __restrict__ dinv,
                                              const float* __restrict__ b,
                                              f16* __restrict__ out) {
    int x = blockIdx.x & 7;
    int j = blockIdx.x >> 3;
    int gsel = j / NBLK_;
    int nb = j - gsel * NBLK_;
    int t = x + (gsel << 3);

    int w = threadIdx.x >> 6;
    int lane = threadIdx.x & 63;
    int q = lane >> 4, m = lane & 15;
    int n0 = nb * 16 + w * 4;    // wave's first node (4-aligned)
    if (n0 >= N_) return;        // tail waves (no barriers in this kernel)
    int base = t * N_;
    const f16* gg = g + (size_t)base * H_;
    const uint16_t* cl = col + (size_t)t * E_;
    int n = n0 + q;              // this 16-lane group's node
    unsigned moB = (unsigned)(m * 8);   // lane's 8-col slice (element offset)

    // CSR bounds for the wave's 4 nodes: one aligned int4 + one scalar
    int4 p4 = *(const int4*)&ptr[base + n0];
    int pend = (n0 + 4 < N_) ? ptr[base + n0 + 4] : E_;
    int begin = (q == 0) ? p4.x : (q == 1) ? p4.y : (q == 2) ? p4.z : p4.w;
    int end   = (q == 0) ? p4.y : (q == 1) ? p4.z : (q == 2) ? p4.w : pend;

    // epilogue operands hoisted (overlap with gathers)
    float dn = dinv[base + n];
    float4 b4a = *(const float4*)&b[m * 8];
    float4 b4b = *(const float4*)&b[m * 8 + 4];

    // zero-row index relative to gg (layout-coupled; see header comment)
    int zidx = 320000 - 5000 * t;

    f16x8 a0 = *(const f16x8*)&gg[((unsigned)n << 7) + moB];  // self-loop row
    f16x8 a1 = {}, a2 = {}, a3 = {}, a4 = {}, a5 = {}, a6 = {}, a7 = {};

    int e0 = begin & ~7;
    int elast = (end - 1) & ~7;          // last chunk start (unused if deg==0)
    unsigned span = (unsigned)(end - begin);
    uint4 cc = *(const uint4*)&cl[e0];   // 16B-aligned; always valid ws memory
    for (int e = e0; e < end; e += 8) {
        int en = e + 8;
        int epf = en < elast ? en : elast;
        uint4 cn = *(const uint4*)&cl[epf];   // prefetch next chunk's cols
        unsigned eb = (unsigned)(e - begin);  // wraps on first chunk; cmp trick ok
        int i0 = (int)(cc.x & 0xFFFFu), i1 = (int)(cc.x >> 16);
        int i2 = (int)(cc.y & 0xFFFFu), i3 = (int)(cc.y >> 16);
        int i4 = (int)(cc.z & 0xFFFFu), i5 = (int)(cc.z >> 16);
        int i6 = (int)(cc.w & 0xFFFFu), i7 = (int)(cc.w >> 16);
        int s0 = (eb + 0 < span) ? i0 : zidx;
        int s1 = (eb + 1 < span) ? i1 : zidx;
        int s2 = (eb + 2 < span) ? i2 : zidx;
        int s3 = (eb + 3 < span) ? i3 : zidx;
        int s4 = (eb + 4 < span) ? i4 : zidx;
        int s5 = (eb + 5 < span) ? i5 : zidx;
        int s6 = (eb + 6 < span) ? i6 : zidx;
        int s7 = (eb + 7 < span) ? i7 : zidx;
        f16x8 v0 = *(const f16x8*)&gg[((unsigned)s0 << 7) + moB];
        f16x8 v1 = *(const f16x8*)&gg[((unsigned)s1 << 7) + moB];
        f16x8 v2 = *(const f16x8*)&gg[((unsigned)s2 << 7) + moB];
        f16x8 v3 = *(const f16x8*)&gg[((unsigned)s3 << 7) + moB];
        f16x8 v4 = *(const f16x8*)&gg[((unsigned)s4 << 7) + moB];
        f16x8 v5 = *(const f16x8*)&gg[((unsigned)s5 << 7) + moB];
        f16x8 v6 = *(const f16x8*)&gg[((unsigned)s6 << 7) + moB];
        f16x8 v7 = *(const f16x8*)&gg[((unsigned)s7 << 7) + moB];
        a0 += v0; a1 += v1; a2 += v2; a3 += v3;
        a4 += v4; a5 += v5; a6 += v6; a7 += v7;
        cc = cn;
    }
    a0 += a1; a2 += a3; a4 += a5; a6 += a7;
    a0 += a2; a4 += a6;
    a0 += a4;

    f16x8 o;
#pragma unroll
    for (int jj = 0; jj < 8; ++jj) {
        float bj = (jj < 4) ? ((const float*)&b4a)[jj] : ((const float*)&b4b)[jj - 4];
        o[jj] = (f16)fast_tanh(dn * (float)a0[jj] + bj);
    }
    *(f16x8*)&out[((size_t)base + n) * H_ + moB] = o;  // contiguous 1 KB wave store
}

// ---------------- node-sum: z[t][c] = sum_n h[t][n][c] ----------------
__global__ __launch_bounds__(256) void k_reduce(const f16* __restrict__ h, float* __restrict__ z) {
    int t = blockIdx.x, seg = blockIdx.y;
    int tid = threadIdx.x;
    int rg = tid >> 5;
    int c = (tid & 31) * 4;
    const f16* p = h + (size_t)t * N_ * H_;
    float4 acc = make_float4(0.f, 0.f, 0.f, 0.f);
    int n0 = seg * 500;
    for (int n = n0 + rg; n < n0 + 500; n += 8) {
        f16x4 v = *(const f16x4*)&p[(size_t)n * H_ + c];
        acc.x += (float)v[0]; acc.y += (float)v[1]; acc.z += (float)v[2]; acc.w += (float)v[3];
    }
    __shared__ float4 part[256];
    part[tid] = acc;
    __syncthreads();
    if (rg == 0) {
        float4 s = part[tid];
#pragma unroll
        for (int j = 1; j < 8; ++j) {
            float4 v = part[(j << 5) + tid];
            s.x += v.x; s.y += v.y; s.z += v.z; s.w += v.w;
        }
        atomicAdd(&z[t * H_ + c + 0], s.x);
        atomicAdd(&z[t * H_ + c + 1], s.y);
        atomicAdd(&z[t * H_ + c + 2], s.z);
        atomicAdd(&z[t * H_ + c + 3], s.w);
    }
}

// ---------------- head stage 1: q,k,v ----------------
__global__ __launch_bounds__(128) void k_qkv(const float* __restrict__ z,
                                             const float* __restrict__ Wq, const float* __restrict__ bq,
                                             const float* __restrict__ Wk, const float* __restrict__ bk,
                                             const float* __restrict__ Wv, const float* __restrict__ bv,
                                             float* __restrict__ q, float* __restrict__ k,
                                             float* __restrict__ v) {
    int t = blockIdx.x, c = threadIdx.x;
    __shared__ float zs[128];
    zs[c] = z[t * 128 + c];
    __syncthreads();
    float aq = bq[c], ak = bk[c], av = bv[c];
    for (int kk = 0; kk < 128; ++kk) {
        float zv = zs[kk];
        aq += zv * Wq[(kk << 7) + c];
        ak += zv * Wk[(kk << 7) + c];
        av += zv * Wv[(kk << 7) + c];
    }
    q[t * 128 + c] = aq;
    k[t * 128 + c] = ak;
    v[t * 128 + c] = av;
}

// ---------------- head stage 2 ----------------
__global__ __launch_bounds__(256) void k_attnmid(
    const float* __restrict__ q, const float* __restrict__ k, const float* __restrict__ v,
    const float* __restrict__ Wo, const float* __restrict__ bo,
    const float* __restrict__ g2, const float* __restrict__ beta2,
    const float* __restrict__ Wm1, const float* __restrict__ bm1,
    const float* __restrict__ Wm2, const float* __restrict__ bm2,
    float* __restrict__ xr) {
    int t = blockIdx.x, tid = threadIdx.x;
    __shared__ float Ks[32 * 128], Vs[32 * 128];
    __shared__ float qs[128], sc[8 * 32], xa[128], hid[512], ys[128];
    __shared__ float redA[128], redB[128];

    for (int i = tid; i < 32 * 128; i += 256) { Ks[i] = k[i]; Vs[i] = v[i]; }
    if (tid < 128) qs[tid] = q[t * 128 + tid];
    __syncthreads();

    {
        int h = tid >> 5, s = tid & 31;
        float d = 0.0f;
#pragma unroll
        for (int kk = 0; kk < 16; ++kk)
            d += qs[(h << 4) + kk] * Ks[(s << 7) + (h << 4) + kk];
        sc[tid] = d * 0.25f;
    }
    __syncthreads();
    if (tid < 8) {
        float m = -1e30f;
        for (int s = 0; s < 32; ++s) m = fmaxf(m, sc[(tid << 5) + s]);
        float l = 0.0f;
        for (int s = 0; s < 32; ++s) { float e = __expf(sc[(tid << 5) + s] - m); sc[(tid << 5) + s] = e; l += e; }
        float inv = 1.0f / l;
        for (int s = 0; s < 32; ++s) sc[(tid << 5) + s] *= inv;
    }
    __syncthreads();
    if (tid < 128) {
        int h = tid >> 4;
        float o = 0.0f;
        for (int s = 0; s < 32; ++s) o += sc[(h << 5) + s] * Vs[(s << 7) + tid];
        qs[tid] = o;
    }
    __syncthreads();
    if (tid < 128) {
        float a = bo[tid];
        for (int kk = 0; kk < 128; ++kk) a += qs[kk] * Wo[(kk << 7) + tid];
        xa[tid] = a;
    }
    __syncthreads();
    for (int j = tid; j < 512; j += 256) {
        float a = bm1[j];
        for (int kk = 0; kk < 128; ++kk) a += xa[kk] * Wm1[(kk << 9) + j];
        hid[j] = fmaxf(a, 0.0f);
    }
    __syncthreads();
    if (tid < 128) {
        float a = bm2[tid];
        for (int j = 0; j < 512; ++j) a += hid[j] * Wm2[(j << 7) + tid];
        ys[tid] = xa[tid] + a;
    }
    __syncthreads();
    if (tid < 128) { redA[tid] = ys[tid]; redB[tid] = ys[tid] * ys[tid]; }
    __syncthreads();
    for (int off = 64; off > 0; off >>= 1) {
        if (tid < off) { redA[tid] += redA[tid + off]; redB[tid] += redB[tid + off]; }
        __syncthreads();
    }
    float mu = redA[0] * (1.0f / 128.0f);
    float var = redB[0] * (1.0f / 128.0f) - mu * mu;
    float rs = rsqrtf(var + 1e-5f);
    if (tid < 128) {
        float yv = (ys[tid] - mu) * rs * g2[tid] + beta2[tid];
        xr[t * 128 + tid] = fmaxf(yv, 0.0f);
    }
}

// ---------------- head stage 3 ----------------
__global__ __launch_bounds__(128) void k_final(const float* __restrict__ xr,
                                               const float* __restrict__ Wl,
                                               const float* __restrict__ bl,
                                               float* __restrict__ out) {
    int tid = threadIdx.x;
    __shared__ float pooled[128];
    float s = 0.0f;
    for (int t = 0; t < 32; ++t) s += xr[t * 128 + tid];
    pooled[tid] = s;
    __syncthreads();
    if (tid < C_) {
        float a = bl[tid];
        for (int kk = 0; kk < 128; ++kk) a += pooled[kk] * Wl[kk * C_ + tid];
        out[tid] = a;
    }
}

extern "C" void kernel_launch(void* const* d_in, const int* in_sizes, int n_in,
                              void* d_out, int out_size, void* d_ws, size_t ws_size,
                              hipStream_t stream) {
    const float* x  = (const float*)d_in[0];
    const int*   ei = (const int*)d_in[1];
    const float* W0 = (const float*)d_in[2];  const float* b0 = (const float*)d_in[3];
    const float* W1 = (const float*)d_in[4];  const float* b1 = (const float*)d_in[5];
    const float* W2 = (const float*)d_in[6];  const float* b2 = (const float*)d_in[7];
    const float* Wq = (const float*)d_in[8];  const float* bq = (const float*)d_in[9];
    const float* Wk = (const float*)d_in[10]; const float* bk = (const float*)d_in[11];
    const float* Wv = (const float*)d_in[12]; const float* bv = (const float*)d_in[13];
    const float* Wo = (const float*)d_in[14]; const float* bo = (const float*)d_in[15];
    const float* g2 = (const float*)d_in[16]; const float* beta2 = (const float*)d_in[17];
    const float* Wm1 = (const float*)d_in[18]; const float* bm1 = (const float*)d_in[19];
    const float* Wm2 = (const float*)d_in[20]; const float* bm2 = (const float*)d_in[21];
    const float* Wl = (const float*)d_in[22]; const float* bl = (const float*)d_in[23];
    float* outp = (float*)d_out;

    const size_t BIG = (size_t)T_ * N_ * H_;
    char* ws = (char*)d_ws;
    float*    dinv = (float*)(ws);
    int*      ptr  = (int*)(ws + 640000);
    uint16_t* col  = (uint16_t*)(ws + 1280000);
    f16*      Wt   = (f16*)(ws + 6400000);
    f16*      P16  = (f16*)(ws + 6498304);
    f16*      Q16  = P16 + BIG;
    float*    z    = (float*)(Q16 + BIG);   // NOTE: k_aggr's zero-row aliases z[0..63]
    float*    zq   = z + 4096;
    float*    zk   = zq + 4096;
    float*    zv   = zk + 4096;
    float*    xr   = zv + 4096;
    int*      part = (int*)P16;   // CSR partials alias P16 (used only before first gemm)

    k_wprep<<<3, 256, 0, stream>>>(W0, W1, W2, Wt);
    k_count<<<NB_ * 32, 256, 0, stream>>>(ei, part);
    k_scan<<<T_, 256, 0, stream>>>(part, ptr, dinv, z);
    k_scatter<<<NB_ * 32, 256, 0, stream>>>(ei, part, col);

    const float* bl_[3] = {b0, b1, b2};
    const int AGGR_BLOCKS = NBLK_ * 32;   // 16 nodes/block, 4 nodes/wave
    k_gemm<true><<<STRIPS * 32, 256, 0, stream>>>(x, Wt, dinv, P16);
    k_aggr<<<AGGR_BLOCKS, 256, 0, stream>>>(ptr, col, P16, dinv, bl_[0], Q16);
    k_gemm<false><<<STRIPS * 32, 256, 0, stream>>>(Q16, Wt + 16384, dinv, P16);
    k_aggr<<<AGGR_BLOCKS, 256, 0, stream>>>(ptr, col, P16, dinv, bl_[1], Q16);
    k_gemm<false><<<STRIPS * 32, 256, 0, stream>>>(Q16, Wt + 32768, dinv, P16);
    k_aggr<<<AGGR_BLOCKS, 256, 0, stream>>>(ptr, col, P16, dinv, bl_[2], Q16);

    k_reduce<<<dim3(T_, 10), 256, 0, stream>>>(Q16, z);

    k_qkv<<<T_, 128, 0, stream>>>(z, Wq, bq, Wk, bk, Wv, bv, zq, zk, zv);
    k_attnmid<<<T_, 256, 0, stream>>>(zq, zk, zv, Wo, bo, g2, beta2,
                                      Wm1, bm1, Wm2, bm2, xr);
    k_final<<<1, 128, 0, stream>>>(xr, Wl, bl, outp);
}

// Round 8
// 488.467 us; speedup vs baseline: 1.0873x; 1.0873x over previous
//
#include <hip/hip_runtime.h>
#include <cstdint>

#define T_ 32
#define N_ 5000
#define E_ 80000
#define H_ 128
#define HD_ 512
#define C_ 10

typedef _Float16 f16;
typedef f16 f16x8 __attribute__((ext_vector_type(8)));
typedef f16 f16x4 __attribute__((ext_vector_type(4)));
typedef f16 f16x2 __attribute__((ext_vector_type(2)));
typedef float f32x4 __attribute__((ext_vector_type(4)));

#define LDA 136   // padded LDS leading dim in f16
#define NB_ 8     // CSR-build blocks per graph
#define EPS_ (E_ / NB_)  // 10000 edges per block
#define NBLK_ 313 // ceil(N_/16) node/row blocks per graph (aggr + gemm tasks)
#define GEMMB 768 // gemm grid: 96 blocks/XCD * 8 (3 blocks/CU at 52KB LDS)

__device__ inline int addpk(int a, int b) {
    f16x2 x = __builtin_bit_cast(f16x2, a);
    f16x2 y = __builtin_bit_cast(f16x2, b);
    f16x2 r = x + y;
    return __builtin_bit_cast(int, r);
}

__device__ inline float fast_tanh(float x) {
    return 1.0f - 2.0f / (__expf(2.0f * x) + 1.0f);
}

__device__ inline f16x8 cvt8(float4 a, float4 b) {
    return (f16x8){(f16)a.x, (f16)a.y, (f16)a.z, (f16)a.w,
                   (f16)b.x, (f16)b.y, (f16)b.z, (f16)b.w};
}

// ---------------- CSR build, LDS-atomic (no global atomics) ----------------
__global__ __launch_bounds__(256) void k_count(const int* __restrict__ ei, int* __restrict__ part) {
    __shared__ int cnt[N_];
    int blk = blockIdx.x;
    int t = blk & 31, seg = blk >> 5;
    int tid = threadIdx.x;
    for (int i = tid; i < N_; i += 256) cnt[i] = 0;
    __syncthreads();
    const int* dst = ei + (size_t)t * 2 * E_ + E_ + seg * EPS_;
    for (int e = tid * 4; e < EPS_; e += 1024) {
        int4 d = *(const int4*)&dst[e];
        atomicAdd(&cnt[d.x], 1);
        atomicAdd(&cnt[d.y], 1);
        atomicAdd(&cnt[d.z], 1);
        atomicAdd(&cnt[d.w], 1);
    }
    __syncthreads();
    int* p = part + (t * NB_ + seg) * N_;
    for (int i = tid * 4; i < N_; i += 1024) *(int4*)&p[i] = *(const int4*)&cnt[i];
}

// ---------------- scan v2: coalesced degree/fixup phases, LDS-staged scan ----------------
__global__ __launch_bounds__(256) void k_scan(int* __restrict__ part, int* __restrict__ ptr,
                                              float* __restrict__ dinv, float* __restrict__ z) {
    __shared__ int cnt[N_];      // degree, then start offset
    __shared__ int red[256];
    int t = blockIdx.x, tid = threadIdx.x;
    int base = t * N_;
    if (tid < 128) z[t * 128 + tid] = 0.0f;   // folded zinit (also the aggr zero-row source)
    int* pp = part + t * NB_ * N_;

    // Phase A: coalesced degree computation
    for (int i = tid; i < N_; i += 256) {
        int c = 0;
#pragma unroll
        for (int s = 0; s < NB_; ++s) c += pp[s * N_ + i];
        cnt[i] = c;
        dinv[base + i] = rsqrtf((float)(c + 1));  // +1 self-loop
    }
    __syncthreads();

    // Phase B: block scan over blocked 20-element runs (LDS source)
    int vals[20];
    int sum = 0;
#pragma unroll
    for (int j = 0; j < 20; ++j) {
        int i = tid * 20 + j;
        int c = (i < N_) ? cnt[i] : 0;
        vals[j] = sum;
        sum += c;
    }
    red[tid] = sum;
    __syncthreads();
    for (int off = 1; off < 256; off <<= 1) {
        int v = (tid >= off) ? red[tid - off] : 0;
        __syncthreads();
        red[tid] += v;
        __syncthreads();
    }
    int prev = (tid > 0) ? red[tid - 1] : 0;
#pragma unroll
    for (int j = 0; j < 20; ++j) {
        int i = tid * 20 + j;
        if (i < N_) cnt[i] = prev + vals[j];   // overwrite degree with start offset
    }
    __syncthreads();

    // Phase C: coalesced ptr write + per-segment running-offset fixup
    for (int i = tid; i < N_; i += 256) {
        int run = cnt[i];
        ptr[base + i] = run;
#pragma unroll
        for (int s = 0; s < NB_; ++s) {
            int c = pp[s * N_ + i];
            pp[s * N_ + i] = run;
            run += c;
        }
    }
}

__global__ __launch_bounds__(256) void k_scatter(const int* __restrict__ ei,
                                                 const int* __restrict__ part,
                                                 uint16_t* __restrict__ col) {
    __shared__ int cur[N_];
    int blk = blockIdx.x;
    int t = blk & 31, seg = blk >> 5;
    int tid = threadIdx.x;
    const int* off = part + (t * NB_ + seg) * N_;
    for (int i = tid * 4; i < N_; i += 1024) *(int4*)&cur[i] = *(const int4*)&off[i];
    __syncthreads();
    const int* src = ei + (size_t)t * 2 * E_ + seg * EPS_;
    const int* dst = src + E_;
    uint16_t* cl = col + (size_t)t * E_;
    for (int e = tid * 4; e < EPS_; e += 1024) {
        int4 s4 = *(const int4*)&src[e];
        int4 d4 = *(const int4*)&dst[e];
        cl[atomicAdd(&cur[d4.x], 1)] = (uint16_t)s4.x;
        cl[atomicAdd(&cur[d4.y], 1)] = (uint16_t)s4.y;
        cl[atomicAdd(&cur[d4.z], 1)] = (uint16_t)s4.z;
        cl[atomicAdd(&cur[d4.w], 1)] = (uint16_t)s4.w;
    }
}

// ---------------- weight prep: Wt[l][c][k] = (f16)W_l[k][c] ----------------
__global__ __launch_bounds__(256) void k_wprep(const float* __restrict__ W0,
                                               const float* __restrict__ W1,
                                               const float* __restrict__ W2,
                                               f16* __restrict__ Wt) {
    const float* W = (blockIdx.x == 0) ? W0 : (blockIdx.x == 1) ? W1 : W2;
    f16* dst = Wt + blockIdx.x * 16384;
    for (int idx = threadIdx.x; idx < 16384; idx += 256) {
        int c = idx >> 7, k = idx & 127;
        dst[idx] = (f16)W[k * 128 + c];
    }
}

// ---------------- MFMA GEMM v5: barrier-free streaming ----------------
// v4 (prefetch + 4 barriers/tile) measured MfmaUtil 2.9%, VALUBusy 3.9%,
// occupancy 24% at 1.2 TB/s -- 3.5x off the BW floor, barrier-coupled latency.
// K=128 fits one wave's MFMA fragments: NO inter-wave A sharing exists. So:
// stage Ws once -> ONE barrier -> waves grid-stride independent 16-row tasks.
// Per task: A direct global->reg (128B-segment coalesced), 32 MFMA, dinv scale,
// transpose via per-wave PRIVATE LDS slab (in-order DS per wave; lgkmcnt only,
// no barrier), then 4 perfectly-coalesced 1KB wave stores. Latency hidden by
// 12 independent waves/CU (TLP), like k_aggr. Task order graph-major per XCD
// (x = blk&7), matching k_aggr so g stays in the producer XCD's L2.
template <bool F32IN>
__global__ __launch_bounds__(256, 3) void k_gemm(const void* __restrict__ in_,
                                                 const f16* __restrict__ Wt,  // [c][k]
                                                 const float* __restrict__ dinv,
                                                 f16* __restrict__ g) {
    __shared__ f16 Ws[128 * LDA];
    __shared__ f16 slab[4][16 * LDA];
    int tid = threadIdx.x;
    {
        int c = tid >> 1, hf = tid & 1;
        const f16* src = Wt + c * 128 + hf * 64;
        f16* dst = Ws + c * LDA + hf * 64;
#pragma unroll
        for (int j = 0; j < 8; ++j) *(f16x8*)&dst[j * 8] = *(const f16x8*)&src[j * 8];
    }
    __syncthreads();   // the ONLY barrier; waves run free below

    int xc = blockIdx.x & 7;
    int jb = blockIdx.x >> 3;            // 0..95 per XCD
    int w = tid >> 6, lane = tid & 63;
    int m = lane & 15, q = lane >> 4;
    int co = q * 8;
    f16* sl = slab[w];
    int srow = lane >> 4;                // store row-within-quad
    int scol = (lane & 15) * 8;          // store col

    for (int task = jb * 4 + w; task < 4 * NBLK_; task += 384) {
        int gsel = task / NBLK_;
        int tile = task - gsel * NBLK_;
        int t = xc + (gsel << 3);
        int base = t * N_;
        int r0 = tile * 16;
        int rowA = r0 + m; if (rowA >= N_) rowA = N_ - 1;   // clamp (not stored)

        // A fragments: direct global -> registers
        f16x8 a0, a1, a2, a3;
        if (F32IN) {
            const float* src = (const float*)in_ + (((size_t)(base + rowA)) << 7) + co;
            float4 u0 = *(const float4*)&src[0];
            float4 u1 = *(const float4*)&src[4];
            float4 u2 = *(const float4*)&src[32];
            float4 u3 = *(const float4*)&src[36];
            float4 u4 = *(const float4*)&src[64];
            float4 u5 = *(const float4*)&src[68];
            float4 u6 = *(const float4*)&src[96];
            float4 u7 = *(const float4*)&src[100];
            a0 = cvt8(u0, u1); a1 = cvt8(u2, u3); a2 = cvt8(u4, u5); a3 = cvt8(u6, u7);
        } else {
            const f16* src = (const f16*)in_ + (((size_t)(base + rowA)) << 7) + co;
            a0 = *(const f16x8*)&src[0];
            a1 = *(const f16x8*)&src[32];
            a2 = *(const f16x8*)&src[64];
            a3 = *(const f16x8*)&src[96];
        }

        f32x4 acc[8];
#pragma unroll
        for (int n = 0; n < 8; ++n) acc[n] = (f32x4){0.f, 0.f, 0.f, 0.f};
#pragma unroll
        for (int n = 0; n < 8; ++n) {
            f16x8 bF = *(const f16x8*)&Ws[(n * 16 + m) * LDA + co];
            acc[n] = __builtin_amdgcn_mfma_f32_16x16x32_f16(a0, bF, acc[n], 0, 0, 0);
        }
#pragma unroll
        for (int n = 0; n < 8; ++n) {
            f16x8 bF = *(const f16x8*)&Ws[(n * 16 + m) * LDA + 32 + co];
            acc[n] = __builtin_amdgcn_mfma_f32_16x16x32_f16(a1, bF, acc[n], 0, 0, 0);
        }
#pragma unroll
        for (int n = 0; n < 8; ++n) {
            f16x8 bF = *(const f16x8*)&Ws[(n * 16 + m) * LDA + 64 + co];
            acc[n] = __builtin_amdgcn_mfma_f32_16x16x32_f16(a2, bF, acc[n], 0, 0, 0);
        }
#pragma unroll
        for (int n = 0; n < 8; ++n) {
            f16x8 bF = *(const f16x8*)&Ws[(n * 16 + m) * LDA + 96 + co];
            acc[n] = __builtin_amdgcn_mfma_f32_16x16x32_f16(a3, bF, acc[n], 0, 0, 0);
        }

        // epilogue: dinv scale -> per-wave slab (transpose) -> coalesced store
#pragma unroll
        for (int i = 0; i < 4; ++i) {
            int rr = q * 4 + i;
            int gr = r0 + rr; if (gr >= N_) gr = N_ - 1;
            float d = dinv[base + gr];
#pragma unroll
            for (int n = 0; n < 8; ++n)
                sl[rr * LDA + n * 16 + m] = (f16)(acc[n][i] * d);
        }
        asm volatile("s_waitcnt lgkmcnt(0)" ::: "memory");  // wave-internal write->read fence
#pragma unroll
        for (int j4 = 0; j4 < 4; ++j4) {
            int row = j4 * 4 + srow;
            f16x8 v = *(const f16x8*)&sl[row * LDA + scol];
            if (r0 + row < N_)
                *(f16x8*)&g[(((size_t)(base + r0 + row)) << 7) + scol] = v;  // 1KB/wave contiguous
        }
    }
}

// ---------------- CSR gather v4 (measured best: 56us, FETCH ~= compulsory; near the
// random-gather L2 throughput ceiling; v5 two-bank pipeline regressed) ----------------
// (1) Graph-major per-XCD block order: XCD = blk&7; one graph's gather set
//     (~2.7MB) stays resident in the 4MB XCD L2 (FETCH 105 -> 23MB).
// (2) 8-aligned edge chunks: one dwordx4 col load per 8 edges (prefetched one
//     chunk ahead); out-of-range lanes redirected via ONE cndmask to a known-
//     zero row (the z buffer: zeroed by k_scan, first written by k_reduce AFTER
//     all aggrs; row index 320000-5000*t relative to gg). Adds unconditional.
__global__ __launch_bounds__(256) void k_aggr(const int* __restrict__ ptr,
                                              const uint16_t* __restrict__ col,
                                              const f16* __restrict__ g,
                                              const float* __restrict__ dinv,
                                              const float* __restrict__ b,
                                              f16* __restrict__ out) {
    int x = blockIdx.x & 7;
    int j = blockIdx.x >> 3;
    int gsel = j / NBLK_;
    int nb = j - gsel * NBLK_;
    int t = x + (gsel << 3);

    int w = threadIdx.x >> 6;
    int lane = threadIdx.x & 63;
    int q = lane >> 4, m = lane & 15;
    int n0 = nb * 16 + w * 4;    // wave's first node (4-aligned)
    if (n0 >= N_) return;        // tail waves (no barriers in this kernel)
    int base = t * N_;
    const f16* gg = g + (size_t)base * H_;
    const uint16_t* cl = col + (size_t)t * E_;
    int n = n0 + q;              // this 16-lane group's node
    unsigned moB = (unsigned)(m * 8);   // lane's 8-col slice (element offset)

    // CSR bounds for the wave's 4 nodes: one aligned int4 + one scalar
    int4 p4 = *(const int4*)&ptr[base + n0];
    int pend = (n0 + 4 < N_) ? ptr[base + n0 + 4] : E_;
    int begin = (q == 0) ? p4.x : (q == 1) ? p4.y : (q == 2) ? p4.z : p4.w;
    int end   = (q == 0) ? p4.y : (q == 1) ? p4.z : (q == 2) ? p4.w : pend;

    // epilogue operands hoisted (overlap with gathers)
    float dn = dinv[base + n];
    float4 b4a = *(const float4*)&b[m * 8];
    float4 b4b = *(const float4*)&b[m * 8 + 4];

    // zero-row index relative to gg (layout-coupled; see header comment)
    int zidx = 320000 - 5000 * t;

    f16x8 a0 = *(const f16x8*)&gg[((unsigned)n << 7) + moB];  // self-loop row
    f16x8 a1 = {}, a2 = {}, a3 = {}, a4 = {}, a5 = {}, a6 = {}, a7 = {};

    int e0 = begin & ~7;
    int elast = (end - 1) & ~7;          // last chunk start (unused if deg==0)
    unsigned span = (unsigned)(end - begin);
    uint4 cc = *(const uint4*)&cl[e0];   // 16B-aligned; always valid ws memory
    for (int e = e0; e < end; e += 8) {
        int en = e + 8;
        int epf = en < elast ? en : elast;
        uint4 cn = *(const uint4*)&cl[epf];   // prefetch next chunk's cols
        unsigned eb = (unsigned)(e - begin);  // wraps on first chunk; cmp trick ok
        int i0 = (int)(cc.x & 0xFFFFu), i1 = (int)(cc.x >> 16);
        int i2 = (int)(cc.y & 0xFFFFu), i3 = (int)(cc.y >> 16);
        int i4 = (int)(cc.z & 0xFFFFu), i5 = (int)(cc.z >> 16);
        int i6 = (int)(cc.w & 0xFFFFu), i7 = (int)(cc.w >> 16);
        int s0 = (eb + 0 < span) ? i0 : zidx;
        int s1 = (eb + 1 < span) ? i1 : zidx;
        int s2 = (eb + 2 < span) ? i2 : zidx;
        int s3 = (eb + 3 < span) ? i3 : zidx;
        int s4 = (eb + 4 < span) ? i4 : zidx;
        int s5 = (eb + 5 < span) ? i5 : zidx;
        int s6 = (eb + 6 < span) ? i6 : zidx;
        int s7 = (eb + 7 < span) ? i7 : zidx;
        f16x8 v0 = *(const f16x8*)&gg[((unsigned)s0 << 7) + moB];
        f16x8 v1 = *(const f16x8*)&gg[((unsigned)s1 << 7) + moB];
        f16x8 v2 = *(const f16x8*)&gg[((unsigned)s2 << 7) + moB];
        f16x8 v3 = *(const f16x8*)&gg[((unsigned)s3 << 7) + moB];
        f16x8 v4 = *(const f16x8*)&gg[((unsigned)s4 << 7) + moB];
        f16x8 v5 = *(const f16x8*)&gg[((unsigned)s5 << 7) + moB];
        f16x8 v6 = *(const f16x8*)&gg[((unsigned)s6 << 7) + moB];
        f16x8 v7 = *(const f16x8*)&gg[((unsigned)s7 << 7) + moB];
        a0 += v0; a1 += v1; a2 += v2; a3 += v3;
        a4 += v4; a5 += v5; a6 += v6; a7 += v7;
        cc = cn;
    }
    a0 += a1; a2 += a3; a4 += a5; a6 += a7;
    a0 += a2; a4 += a6;
    a0 += a4;

    f16x8 o;
#pragma unroll
    for (int jj = 0; jj < 8; ++jj) {
        float bj = (jj < 4) ? ((const float*)&b4a)[jj] : ((const float*)&b4b)[jj - 4];
        o[jj] = (f16)fast_tanh(dn * (float)a0[jj] + bj);
    }
    *(f16x8*)&out[((size_t)base + n) * H_ + moB] = o;  // contiguous 1 KB wave store
}

// ---------------- node-sum: z[t][c] = sum_n h[t][n][c] ----------------
__global__ __launch_bounds__(256) void k_reduce(const f16* __restrict__ h, float* __restrict__ z) {
    int t = blockIdx.x, seg = blockIdx.y;
    int tid = threadIdx.x;
    int rg = tid >> 5;
    int c = (tid & 31) * 4;
    const f16* p = h + (size_t)t * N_ * H_;
    float4 acc = make_float4(0.f, 0.f, 0.f, 0.f);
    int n0 = seg * 500;
    for (int n = n0 + rg; n < n0 + 500; n += 8) {
        f16x4 v = *(const f16x4*)&p[(size_t)n * H_ + c];
        acc.x += (float)v[0]; acc.y += (float)v[1]; acc.z += (float)v[2]; acc.w += (float)v[3];
    }
    __shared__ float4 part[256];
    part[tid] = acc;
    __syncthreads();
    if (rg == 0) {
        float4 s = part[tid];
#pragma unroll
        for (int j = 1; j < 8; ++j) {
            float4 v = part[(j << 5) + tid];
            s.x += v.x; s.y += v.y; s.z += v.z; s.w += v.w;
        }
        atomicAdd(&z[t * H_ + c + 0], s.x);
        atomicAdd(&z[t * H_ + c + 1], s.y);
        atomicAdd(&z[t * H_ + c + 2], s.z);
        atomicAdd(&z[t * H_ + c + 3], s.w);
    }
}

// ---------------- head stage 1: q,k,v ----------------
__global__ __launch_bounds__(128) void k_qkv(const float* __restrict__ z,
                                             const float* __restrict__ Wq, const float* __restrict__ bq,
                                             const float* __restrict__ Wk, const float* __restrict__ bk,
                                             const float* __restrict__ Wv, const float* __restrict__ bv,
                                             float* __restrict__ q, float* __restrict__ k,
                                             float* __restrict__ v) {
    int t = blockIdx.x, c = threadIdx.x;
    __shared__ float zs[128];
    zs[c] = z[t * 128 + c];
    __syncthreads();
    float aq = bq[c], ak = bk[c], av = bv[c];
    for (int kk = 0; kk < 128; ++kk) {
        float zv = zs[kk];
        aq += zv * Wq[(kk << 7) + c];
        ak += zv * Wk[(kk << 7) + c];
        av += zv * Wv[(kk << 7) + c];
    }
    q[t * 128 + c] = aq;
    k[t * 128 + c] = ak;
    v[t * 128 + c] = av;
}

// ---------------- head stage 2 ----------------
__global__ __launch_bounds__(256) void k_attnmid(
    const float* __restrict__ q, const float* __restrict__ k, const float* __restrict__ v,
    const float* __restrict__ Wo, const float* __restrict__ bo,
    const float* __restrict__ g2, const float* __restrict__ beta2,
    const float* __restrict__ Wm1, const float* __restrict__ bm1,
    const float* __restrict__ Wm2, const float* __restrict__ bm2,
    float* __restrict__ xr) {
    int t = blockIdx.x, tid = threadIdx.x;
    __shared__ float Ks[32 * 128], Vs[32 * 128];
    __shared__ float qs[128], sc[8 * 32], xa[128], hid[512], ys[128];
    __shared__ float redA[128], redB[128];

    for (int i = tid; i < 32 * 128; i += 256) { Ks[i] = k[i]; Vs[i] = v[i]; }
    if (tid < 128) qs[tid] = q[t * 128 + tid];
    __syncthreads();

    {
        int h = tid >> 5, s = tid & 31;
        float d = 0.0f;
#pragma unroll
        for (int kk = 0; kk < 16; ++kk)
            d += qs[(h << 4) + kk] * Ks[(s << 7) + (h << 4) + kk];
        sc[tid] = d * 0.25f;
    }
    __syncthreads();
    if (tid < 8) {
        float m = -1e30f;
        for (int s = 0; s < 32; ++s) m = fmaxf(m, sc[(tid << 5) + s]);
        float l = 0.0f;
        for (int s = 0; s < 32; ++s) { float e = __expf(sc[(tid << 5) + s] - m); sc[(tid << 5) + s] = e; l += e; }
        float inv = 1.0f / l;
        for (int s = 0; s < 32; ++s) sc[(tid << 5) + s] *= inv;
    }
    __syncthreads();
    if (tid < 128) {
        int h = tid >> 4;
        float o = 0.0f;
        for (int s = 0; s < 32; ++s) o += sc[(h << 5) + s] * Vs[(s << 7) + tid];
        qs[tid] = o;
    }
    __syncthreads();
    if (tid < 128) {
        float a = bo[tid];
        for (int kk = 0; kk < 128; ++kk) a += qs[kk] * Wo[(kk << 7) + tid];
        xa[tid] = a;
    }
    __syncthreads();
    for (int j = tid; j < 512; j += 256) {
        float a = bm1[j];
        for (int kk = 0; kk < 128; ++kk) a += xa[kk] * Wm1[(kk << 9) + j];
        hid[j] = fmaxf(a, 0.0f);
    }
    __syncthreads();
    if (tid < 128) {
        float a = bm2[tid];
        for (int j = 0; j < 512; ++j) a += hid[j] * Wm2[(j << 7) + tid];
        ys[tid] = xa[tid] + a;
    }
    __syncthreads();
    if (tid < 128) { redA[tid] = ys[tid]; redB[tid] = ys[tid] * ys[tid]; }
    __syncthreads();
    for (int off = 64; off > 0; off >>= 1) {
        if (tid < off) { redA[tid] += redA[tid + off]; redB[tid] += redB[tid + off]; }
        __syncthreads();
    }
    float mu = redA[0] * (1.0f / 128.0f);
    float var = redB[0] * (1.0f / 128.0f) - mu * mu;
    float rs = rsqrtf(var + 1e-5f);
    if (tid < 128) {
        float yv = (ys[tid] - mu) * rs * g2[tid] + beta2[tid];
        xr[t * 128 + tid] = fmaxf(yv, 0.0f);
    }
}

// ---------------- head stage 3 ----------------
__global__ __launch_bounds__(128) void k_final(const float* __restrict__ xr,
                                               const float* __restrict__ Wl,
                                               const float* __restrict__ bl,
                                               float* __restrict__ out) {
    int tid = threadIdx.x;
    __shared__ float pooled[128];
    float s = 0.0f;
    for (int t = 0; t < 32; ++t) s += xr[t * 128 + tid];
    pooled[tid] = s;
    __syncthreads();
    if (tid < C_) {
        float a = bl[tid];
        for (int kk = 0; kk < 128; ++kk) a += pooled[kk] * Wl[kk * C_ + tid];
        out[tid] = a;
    }
}

extern "C" void kernel_launch(void* const* d_in, const int* in_sizes, int n_in,
                              void* d_out, int out_size, void* d_ws, size_t ws_size,
                              hipStream_t stream) {
    const float* x  = (const float*)d_in[0];
    const int*   ei = (const int*)d_in[1];
    const float* W0 = (const float*)d_in[2];  const float* b0 = (const float*)d_in[3];
    const float* W1 = (const float*)d_in[4];  const float* b1 = (const float*)d_in[5];
    const float* W2 = (const float*)d_in[6];  const float* b2 = (const float*)d_in[7];
    const float* Wq = (const float*)d_in[8];  const float* bq = (const float*)d_in[9];
    const float* Wk = (const float*)d_in[10]; const float* bk = (const float*)d_in[11];
    const float* Wv = (const float*)d_in[12]; const float* bv = (const float*)d_in[13];
    const float* Wo = (const float*)d_in[14]; const float* bo = (const float*)d_in[15];
    const float* g2 = (const float*)d_in[16]; const float* beta2 = (const float*)d_in[17];
    const float* Wm1 = (const float*)d_in[18]; const float* bm1 = (const float*)d_in[19];
    const float* Wm2 = (const float*)d_in[20]; const float* bm2 = (const float*)d_in[21];
    const float* Wl = (const float*)d_in[22]; const float* bl = (const float*)d_in[23];
    float* outp = (float*)d_out;

    const size_t BIG = (size_t)T_ * N_ * H_;
    char* ws = (char*)d_ws;
    float*    dinv = (float*)(ws);
    int*      ptr  = (int*)(ws + 640000);
    uint16_t* col  = (uint16_t*)(ws + 1280000);
    f16*      Wt   = (f16*)(ws + 6400000);
    f16*      P16  = (f16*)(ws + 6498304);
    f16*      Q16  = P16 + BIG;
    float*    z    = (float*)(Q16 + BIG);   // NOTE: k_aggr's zero-row aliases z[0..63]
    float*    zq   = z + 4096;
    float*    zk   = zq + 4096;
    float*    zv   = zk + 4096;
    float*    xr   = zv + 4096;
    int*      part = (int*)P16;   // CSR partials alias P16 (used only before first gemm)

    k_wprep<<<3, 256, 0, stream>>>(W0, W1, W2, Wt);
    k_count<<<NB_ * 32, 256, 0, stream>>>(ei, part);
    k_scan<<<T_, 256, 0, stream>>>(part, ptr, dinv, z);
    k_scatter<<<NB_ * 32, 256, 0, stream>>>(ei, part, col);

    const float* bl_[3] = {b0, b1, b2};
    const int AGGR_BLOCKS = NBLK_ * 32;   // 16 nodes/block, 4 nodes/wave
    k_gemm<true><<<GEMMB, 256, 0, stream>>>(x, Wt, dinv, P16);
    k_aggr<<<AGGR_BLOCKS, 256, 0, stream>>>(ptr, col, P16, dinv, bl_[0], Q16);
    k_gemm<false><<<GEMMB, 256, 0, stream>>>(Q16, Wt + 16384, dinv, P16);
    k_aggr<<<AGGR_BLOCKS, 256, 0, stream>>>(ptr, col, P16, dinv, bl_[1], Q16);
    k_gemm<false><<<GEMMB, 256, 0, stream>>>(Q16, Wt + 32768, dinv, P16);
    k_aggr<<<AGGR_BLOCKS, 256, 0, stream>>>(ptr, col, P16, dinv, bl_[2], Q16);

    k_reduce<<<dim3(T_, 10), 256, 0, stream>>>(Q16, z);

    k_qkv<<<T_, 128, 0, stream>>>(z, Wq, bq, Wk, bk, Wv, bv, zq, zk, zv);
    k_attnmid<<<T_, 256, 0, stream>>>(zq, zk, zv, Wo, bo, g2, beta2,
                                      Wm1, bm1, Wm2, bm2, xr);
    k_final<<<1, 128, 0, stream>>>(xr, Wl, bl, outp);
}